// Round 1
// baseline (327.021 us; speedup 1.0000x reference)
//
#include <hip/hip_runtime.h>
#include <hip/hip_bf16.h>

// LSTM: I=32, H=64, O=8, B=4096, T=256, fused single kernel.
// Block = 256 threads (4 waves) handles BR=16 batch rows for all T steps.
// Per step: gates[16x256] = A[16x96] @ Wcat^T[96x256] via mfma_f32_16x16x32_bf16.
// Wave w owns hidden indices j in [16w,16w+16) for ALL 4 gates -> per-lane
// i/f/g/o for same (row,j) -> no cross-wave exchange; c in fp32 registers.

#define T_LEN 256
#define I_SZ  32
#define H_SZ  64
#define O_SZ  8
#define BR    16

typedef __attribute__((ext_vector_type(8))) short short8;
typedef __attribute__((ext_vector_type(4))) float f32x4;

static __device__ __forceinline__ short f2bf(float f) {
    union { __hip_bfloat16 b; short s; } u;
    u.b = __float2bfloat16(f);
    return u.s;
}

static __device__ __forceinline__ float rcp_fast(float x) {
    return __builtin_amdgcn_rcpf(x);
}
static __device__ __forceinline__ float sigf(float x) {
    return rcp_fast(1.0f + __expf(-x));
}
// tanh(x) = 1 - 2/(1+e^{2x}); saturates correctly via inf/0 at extremes.
static __device__ __forceinline__ float tanh_fast(float x) {
    return 1.0f - 2.0f * rcp_fast(1.0f + __expf(2.0f * x));
}

__global__ __launch_bounds__(256, 1)
void lstm_fused_kernel(const float* __restrict__ x,
                       const float* __restrict__ W_ih,
                       const float* __restrict__ W_hh,
                       const float* __restrict__ b_ih,
                       const float* __restrict__ b_hh,
                       const float* __restrict__ W_fc,
                       const float* __restrict__ b_fc,
                       float* __restrict__ out)
{
    // A operand: rows = 16 batch rows, cols k: [0,32)=x_t, [32,96)=h, pad to 104.
    // Row stride 104 shorts = 52 dwords (=4 mod 8) -> conflict-free b128 reads.
    __shared__ short A_lds[16][104];
    __shared__ float Hf[16][64];

    const int tid  = threadIdx.x;
    const int wave = tid >> 6;
    const int lane = tid & 63;
    const int quad = lane >> 4;
    const int nlow = lane & 15;
    const int j    = wave * 16 + nlow;      // hidden index this lane owns, 0..63
    const int b0   = blockIdx.x * BR;

    // ---- Load B fragments (weights) once into registers.
    // B frag layout: lane holds Wcat[col = n][k = quad*8 + e], n = nlow (+ntile*16).
    // N-tile for (gate g, wave w) = g*4 + w -> col = g*64 + j.
    short8 bfrag[4][3];
    for (int g = 0; g < 4; ++g) {
        const int col = g * 64 + j;          // 0..255 gate-row of Wcat
        {
            const float* wr = W_ih + col * I_SZ + quad * 8;  // kt=0: k in [0,32)
            short8 f;
            #pragma unroll
            for (int e = 0; e < 8; ++e) f[e] = f2bf(wr[e]);
            bfrag[g][0] = f;
        }
        #pragma unroll
        for (int kt = 1; kt < 3; ++kt) {     // kt=1,2: k-32 in [0,64) of W_hh
            const float* wr = W_hh + col * H_SZ + (kt - 1) * 32 + quad * 8;
            short8 f;
            #pragma unroll
            for (int e = 0; e < 8; ++e) f[e] = f2bf(wr[e]);
            bfrag[g][kt] = f;
        }
    }
    float bias[4];
    #pragma unroll
    for (int g = 0; g < 4; ++g) bias[g] = b_ih[g * 64 + j] + b_hh[g * 64 + j];

    // ---- init h region of A (k=32..95) to zero (h0 = 0)
    for (int q = tid; q < 16 * 64; q += 256)
        A_lds[q >> 6][32 + (q & 63)] = (short)0;

    float c[4]  = {0.f, 0.f, 0.f, 0.f};
    float hq[4] = {0.f, 0.f, 0.f, 0.f};

    // ---- x staging assignment: thread -> (row, 2 floats)
    const int xr = tid >> 4;                // 0..15
    const int xi = (tid & 15) * 2;          // 0,2,..,30
    const float* xbase = x + ((size_t)(b0 + xr) * T_LEN) * I_SZ + xi;
    float2 xreg = *(const float2*)(xbase);  // prefetch t=0

    for (int t = 0; t < T_LEN; ++t) {
        // write staged x_t (bf16) into A
        A_lds[xr][xi]     = f2bf(xreg.x);
        A_lds[xr][xi + 1] = f2bf(xreg.y);
        __syncthreads();                    // x_t and h_{t-1} visible

        // prefetch next step's x (hidden behind MFMA + activations)
        if (t + 1 < T_LEN) xreg = *(const float2*)(xbase + (t + 1) * I_SZ);

        // A fragments: A[m = nlow][k = kt*32 + quad*8 + e]
        short8 a0 = *(const short8*)&A_lds[nlow][0 * 32 + quad * 8];
        short8 a1 = *(const short8*)&A_lds[nlow][1 * 32 + quad * 8];
        short8 a2 = *(const short8*)&A_lds[nlow][2 * 32 + quad * 8];

        f32x4 acc[4];
        #pragma unroll
        for (int g = 0; g < 4; ++g) {
            f32x4 a = {0.f, 0.f, 0.f, 0.f};
            a = __builtin_amdgcn_mfma_f32_16x16x32_bf16(a0, bfrag[g][0], a, 0, 0, 0);
            a = __builtin_amdgcn_mfma_f32_16x16x32_bf16(a1, bfrag[g][1], a, 0, 0, 0);
            a = __builtin_amdgcn_mfma_f32_16x16x32_bf16(a2, bfrag[g][2], a, 0, 0, 0);
            acc[g] = a;
        }
        __syncthreads();                    // all waves done reading A_lds

        // LSTM cell update; D layout: row = quad*4 + q, col(j) = nlow (+16w)
        #pragma unroll
        for (int q = 0; q < 4; ++q) {
            float iv = sigf(acc[0][q] + bias[0]);
            float fv = sigf(acc[1][q] + bias[1]);
            float gv = tanh_fast(acc[2][q] + bias[2]);
            float ov = sigf(acc[3][q] + bias[3]);
            c[q] = fv * c[q] + iv * gv;
            float hv = ov * tanh_fast(c[q]);
            hq[q] = hv;
            A_lds[quad * 4 + q][32 + j] = f2bf(hv);   // h_t for next step
        }
    }

    // ---- epilogue: out[b0+r][o] = h_T[r] . W_fc[o] + b_fc[o]  (fp32 h)
    #pragma unroll
    for (int q = 0; q < 4; ++q) Hf[quad * 4 + q][j] = hq[q];
    __syncthreads();

    if (tid < BR * O_SZ) {                  // 128 threads
        const int r = tid >> 3;
        const int o = tid & 7;
        const float* wf = W_fc + o * H_SZ;
        float acc = b_fc[o];
        #pragma unroll
        for (int jx = 0; jx < H_SZ; ++jx) acc += Hf[r][jx] * wf[jx];
        out[(size_t)(b0 + r) * O_SZ + o] = acc;
    }
}

extern "C" void kernel_launch(void* const* d_in, const int* in_sizes, int n_in,
                              void* d_out, int out_size, void* d_ws, size_t ws_size,
                              hipStream_t stream) {
    const float* x    = (const float*)d_in[0];
    const float* W_ih = (const float*)d_in[1];
    const float* W_hh = (const float*)d_in[2];
    const float* b_ih = (const float*)d_in[3];
    const float* b_hh = (const float*)d_in[4];
    const float* W_fc = (const float*)d_in[5];
    const float* b_fc = (const float*)d_in[6];
    float* out = (float*)d_out;

    const int B = 4096;
    lstm_fused_kernel<<<dim3(B / BR), dim3(256), 0, stream>>>(
        x, W_ih, W_hh, b_ih, b_hh, W_fc, b_fc, out);
}

// Round 2
// 324.791 us; speedup vs baseline: 1.0069x; 1.0069x over previous
//
#include <hip/hip_runtime.h>
#include <hip/hip_bf16.h>

// LSTM: I=32, H=64, O=8, B=4096, T=256, fused single kernel.
// Round 2: BR=8 rows/block, grid=512 -> 2 blocks/CU (2 waves/SIMD) for latency
// hiding. Gate pre-activations are redistributed through LDS so activation
// (transcendental) work is split evenly over all 256 threads with no waste
// from the half-empty 16x16 MFMA tiles. c-state lives in fp32 registers of
// the owning thread for all 256 steps.

#define T_LEN 256
#define I_SZ  32
#define H_SZ  64
#define O_SZ  8
#define BR    8

typedef __attribute__((ext_vector_type(8))) short short8;
typedef __attribute__((ext_vector_type(4))) float f32x4;

static __device__ __forceinline__ short f2bf(float f) {
    union { __hip_bfloat16 b; short s; } u;
    u.b = __float2bfloat16(f);
    return u.s;
}

static __device__ __forceinline__ float rcp_fast(float x) {
    return __builtin_amdgcn_rcpf(x);
}
static __device__ __forceinline__ float sigf(float x) {
    return rcp_fast(1.0f + __expf(-x));
}
// tanh(x) = 1 - 2/(1+e^{2x}); saturates correctly via inf/0 at extremes.
static __device__ __forceinline__ float tanh_fast(float x) {
    return 1.0f - 2.0f * rcp_fast(1.0f + __expf(2.0f * x));
}

__global__ __launch_bounds__(256, 2)
void lstm_fused_kernel(const float* __restrict__ x,
                       const float* __restrict__ W_ih,
                       const float* __restrict__ W_hh,
                       const float* __restrict__ b_ih,
                       const float* __restrict__ b_hh,
                       const float* __restrict__ W_fc,
                       const float* __restrict__ b_fc,
                       float* __restrict__ out)
{
    // A operand: 16 rows (only 0..7 valid batch rows; 8..15 stay zero),
    // cols k: [0,32)=x_t, [32,96)=h, pad to 104 shorts (52 dwords).
    __shared__ short A_lds[16][104];
    // Gate pre-activations, f32: [gate][row 0..7][j 0..63].
    // Writes: 2 rows x 16 consecutive j per instr -> 2-way (free).
    // Reads: 64 consecutive j per wave -> 2-way (free).
    __shared__ float G[4][BR][64];
    __shared__ float Hf[BR][64];

    const int tid  = threadIdx.x;
    const int wave = tid >> 6;
    const int lane = tid & 63;
    const int quad = lane >> 4;
    const int nlow = lane & 15;
    const int jw   = wave * 16 + nlow;   // gate-col this lane's MFMA tiles own
    const int b0   = blockIdx.x * BR;

    // ---- B fragments (weights) once into registers.
    // lane holds Wcat[col][k = quad*8 + e]; col = g*64 + jw.
    short8 bfrag[4][3];
    for (int g = 0; g < 4; ++g) {
        const int col = g * 64 + jw;
        {
            const float* wr = W_ih + col * I_SZ + quad * 8;   // k in [0,32)
            short8 f;
            #pragma unroll
            for (int e = 0; e < 8; ++e) f[e] = f2bf(wr[e]);
            bfrag[g][0] = f;
        }
        #pragma unroll
        for (int kt = 1; kt < 3; ++kt) {                      // k-32 in [0,64)
            const float* wr = W_hh + col * H_SZ + (kt - 1) * 32 + quad * 8;
            short8 f;
            #pragma unroll
            for (int e = 0; e < 8; ++e) f[e] = f2bf(wr[e]);
            bfrag[g][kt] = f;
        }
    }

    // ---- activation-role constants: thread -> cells (r0, jr) and (r1, jr)
    const int jr = tid & 63;
    const int r0 = tid >> 6;             // 0..3
    const int r1 = r0 + 4;               // 4..7
    float bias[4];
    #pragma unroll
    for (int g = 0; g < 4; ++g) bias[g] = b_ih[g * 64 + jr] + b_hh[g * 64 + jr];

    // ---- x staging: thread -> (row xr, col xi), 1 float/step
    const int xr = tid >> 5;             // 0..7
    const int xi = tid & 31;             // 0..31
    const float* xbase = x + ((size_t)(b0 + xr) * T_LEN) * I_SZ + xi;
    float xreg = xbase[0];               // prefetch t=0

    // ---- zero all of A (h0 = 0; rows 8..15 must be clean for MFMA reads)
    for (int q = tid; q < 16 * 104; q += 256) ((short*)A_lds)[q] = (short)0;

    float c0 = 0.f, c1 = 0.f, hv0 = 0.f, hv1 = 0.f;

    for (int t = 0; t < T_LEN; ++t) {
        A_lds[xr][xi] = f2bf(xreg);          // x_t
        __syncthreads();                     // b1: x_t + h_{t-1} visible;
                                             //     prev-step G reads done
        if (t + 1 < T_LEN) xreg = xbase[(t + 1) * I_SZ];

        // A fragments: A[m = nlow][k = kt*32 + quad*8 + e]
        short8 a0 = *(const short8*)&A_lds[nlow][0 * 32 + quad * 8];
        short8 a1 = *(const short8*)&A_lds[nlow][1 * 32 + quad * 8];
        short8 a2 = *(const short8*)&A_lds[nlow][2 * 32 + quad * 8];

        f32x4 acc[4];
        #pragma unroll
        for (int g = 0; g < 4; ++g) {
            f32x4 a = {0.f, 0.f, 0.f, 0.f};
            a = __builtin_amdgcn_mfma_f32_16x16x32_bf16(a0, bfrag[g][0], a, 0, 0, 0);
            a = __builtin_amdgcn_mfma_f32_16x16x32_bf16(a1, bfrag[g][1], a, 0, 0, 0);
            a = __builtin_amdgcn_mfma_f32_16x16x32_bf16(a2, bfrag[g][2], a, 0, 0, 0);
            acc[g] = a;
        }
        // D layout: row = quad*4 + q, col = jw. Rows 0..7 valid -> quads 0,1.
        if (quad < 2) {
            #pragma unroll
            for (int g = 0; g < 4; ++g) {
                #pragma unroll
                for (int q = 0; q < 4; ++q)
                    G[g][quad * 4 + q][jw] = acc[g][q];
            }
        }
        __syncthreads();                     // b2: G visible; A reads done

        // ---- cell update, 2 cells/thread, all lanes active
        float p0[4], p1[4];
        #pragma unroll
        for (int g = 0; g < 4; ++g) {
            p0[g] = G[g][r0][jr] + bias[g];
            p1[g] = G[g][r1][jr] + bias[g];
        }
        {
            float iv = sigf(p0[0]), fv = sigf(p0[1]);
            float gv = tanh_fast(p0[2]), ov = sigf(p0[3]);
            c0 = fv * c0 + iv * gv;
            hv0 = ov * tanh_fast(c0);
            A_lds[r0][32 + jr] = f2bf(hv0);
        }
        {
            float iv = sigf(p1[0]), fv = sigf(p1[1]);
            float gv = tanh_fast(p1[2]), ov = sigf(p1[3]);
            c1 = fv * c1 + iv * gv;
            hv1 = ov * tanh_fast(c1);
            A_lds[r1][32 + jr] = f2bf(hv1);
        }
    }

    // ---- epilogue: out[b0+r][o] = h_T[r] . W_fc[o] + b_fc[o]  (fp32 h)
    Hf[r0][jr] = hv0;
    Hf[r1][jr] = hv1;
    __syncthreads();

    if (tid < BR * O_SZ) {                   // 64 threads
        const int r = tid >> 3;
        const int o = tid & 7;
        const float* wf = W_fc + o * H_SZ;
        float acc = b_fc[o];
        #pragma unroll
        for (int jx = 0; jx < H_SZ; ++jx) acc += Hf[r][jx] * wf[jx];
        out[(size_t)(b0 + r) * O_SZ + o] = acc;
    }
}

extern "C" void kernel_launch(void* const* d_in, const int* in_sizes, int n_in,
                              void* d_out, int out_size, void* d_ws, size_t ws_size,
                              hipStream_t stream) {
    const float* x    = (const float*)d_in[0];
    const float* W_ih = (const float*)d_in[1];
    const float* W_hh = (const float*)d_in[2];
    const float* b_ih = (const float*)d_in[3];
    const float* b_hh = (const float*)d_in[4];
    const float* W_fc = (const float*)d_in[5];
    const float* b_fc = (const float*)d_in[6];
    float* out = (float*)d_out;

    const int B = 4096;
    lstm_fused_kernel<<<dim3(B / BR), dim3(256), 0, stream>>>(
        x, W_ih, W_hh, b_ih, b_hh, W_fc, b_fc, out);
}